// Round 5
// baseline (128.288 us; speedup 1.0000x reference)
//
#include <hip/hip_runtime.h>
#include <hip/hip_bf16.h>

#define NBATCH 4
#define NN 4096
#define NF 128
#define NU 64
#define CH 16              // correction chunk length
#define NCH (NN / CH)      // 256 chunks per batch
#define LEAKY 0.2f

// ---------------------------------------------------------------------------
// k1: h[b,n,u] = sum_f x[b,n,f]*W[f,u]; f1 = h.a1, f2 = h.a2.
// 1024 blocks x 256 thr; wave owns 4 rows; lane = u. NO LDS:
// x rows are wave-uniform -> s_load via readfirstlane'd base; W col in VGPRs.
// ---------------------------------------------------------------------------
__global__ __launch_bounds__(256) void k1_h(
    const float* __restrict__ x, const float* __restrict__ W,
    const float* __restrict__ a,
    float* __restrict__ h, float* __restrict__ f1, float* __restrict__ f2) {
  int tid = threadIdx.x;
  int u = tid & 63;
  int wv = tid >> 6;
  int row0 = __builtin_amdgcn_readfirstlane(blockIdx.x * 16 + wv * 4);
  const float* xb = x + (size_t)row0 * NF;   // wave-uniform pointer
  float acc[4] = {0.f, 0.f, 0.f, 0.f};
#pragma unroll
  for (int ft = 0; ft < NF; ft += 32) {
    float w[32];
#pragma unroll
    for (int i = 0; i < 32; ++i) w[i] = W[(ft + i) * NU + u];
#pragma unroll
    for (int r = 0; r < 4; ++r) {
      const float* xr = xb + r * NF + ft;    // uniform -> s_load
#pragma unroll
      for (int i = 0; i < 32; ++i) acc[r] += xr[i] * w[i];
    }
  }
  float a1 = a[u], a2 = a[NU + u];
#pragma unroll
  for (int r = 0; r < 4; ++r) {
    int grow = row0 + r;
    h[(size_t)grow * NU + u] = acc[r];
    float p1 = acc[r] * a1, p2 = acc[r] * a2;
#pragma unroll
    for (int off = 32; off >= 1; off >>= 1) {
      p1 += __shfl_xor(p1, off, 64);
      p2 += __shfl_xor(p2, off, 64);
    }
    if (u == 0) { f1[grow] = p1; f2[grow] = p2; }
  }
}

// ---------------------------------------------------------------------------
// k2a: partial rank counts. grid = b(4) x jc(8: 512 j) x kc(16: 256 k) = 512.
// Thread owns 2 j's; float4 LDS reads (8 compares per DS instr).
// ---------------------------------------------------------------------------
__global__ __launch_bounds__(256) void k2a_count(
    const float* __restrict__ f2, unsigned short* __restrict__ pc) {
  __shared__ float fsk[256];
  int b = blockIdx.x >> 7;          // 128 blocks per batch
  int jc = (blockIdx.x >> 4) & 7;
  int kc = blockIdx.x & 15;
  int tid = threadIdx.x;
  const float* f2b = f2 + b * NN;
  fsk[tid] = f2b[kc * 256 + tid];
  __syncthreads();
  int j0 = jc * 512 + tid;
  int j1 = j0 + 256;
  float my0 = f2b[j0], my1 = f2b[j1];
  int k0g = kc * 256;
  int cnt0 = 0, cnt1 = 0;
#pragma unroll 8
  for (int k = 0; k < 256; k += 4) {
    float4 v = *(const float4*)&fsk[k];
    int kg = k0g + k;
    cnt0 += (v.x < my0) || (v.x == my0 && kg + 0 < j0);
    cnt0 += (v.y < my0) || (v.y == my0 && kg + 1 < j0);
    cnt0 += (v.z < my0) || (v.z == my0 && kg + 2 < j0);
    cnt0 += (v.w < my0) || (v.w == my0 && kg + 3 < j0);
    cnt1 += (v.x < my1) || (v.x == my1 && kg + 0 < j1);
    cnt1 += (v.y < my1) || (v.y == my1 && kg + 1 < j1);
    cnt1 += (v.z < my1) || (v.z == my1 && kg + 2 < j1);
    cnt1 += (v.w < my1) || (v.w == my1 && kg + 3 < j1);
  }
  size_t base = ((size_t)(b * 16 + kc)) * NN;
  pc[base + j0] = (unsigned short)cnt0;
  pc[base + j1] = (unsigned short)cnt1;
}

// ---------------------------------------------------------------------------
// k2b: rank = sum of 16 partials; scatter packed {f2, e^f2, e^.2f2, perm}
// plus a plain sorted-f2 array for the k4 search.
// ---------------------------------------------------------------------------
__global__ __launch_bounds__(256) void k2b_scatter(
    const float* __restrict__ f2, const unsigned short* __restrict__ pc,
    float4* __restrict__ sdat, float* __restrict__ f2s) {
  int b = blockIdx.x >> 4;
  int jc = blockIdx.x & 15;
  int j = jc * 256 + threadIdx.x;
  float my = f2[b * NN + j];
  int rank = 0;
#pragma unroll
  for (int kc = 0; kc < 16; ++kc)
    rank += pc[((size_t)(b * 16 + kc)) * NN + j];
  int o = b * NN + rank;
  float4 v;
  v.x = my; v.y = expf(my); v.z = expf(LEAKY * my); v.w = __int_as_float(j);
  sdat[o] = v;
  f2s[o] = my;
}

// ---------------------------------------------------------------------------
// k3: chunk sums. One wave per chunk of CH=16 sorted els; lane = u.
// 256 blocks x 4 waves.
// ---------------------------------------------------------------------------
__global__ __launch_bounds__(256) void k3_csum(
    const float* __restrict__ h, const float4* __restrict__ sdat,
    float* __restrict__ Pvhi, float* __restrict__ Pvlo,
    float* __restrict__ Pshi, float* __restrict__ Pslo) {
  int u = threadIdx.x & 63;
  int wv = threadIdx.x >> 6;
  int cg = blockIdx.x * 4 + wv;     // global chunk 0..1023
  int b = cg >> 8;                  // 256 chunks per batch
  int c = cg & (NCH - 1);
  int k0 = b * NN + c * CH;
  const float* hb = h + (size_t)b * NN * NU;
  float ah = 0.f, al = 0.f, sh = 0.f, sl = 0.f;
#pragma unroll
  for (int k = 0; k < CH; ++k) {
    float4 e = sdat[k0 + k];
    int j = __float_as_int(e.w);
    float hv = hb[(size_t)j * NU + u];
    ah += e.y * hv; al += e.z * hv; sh += e.y; sl += e.z;
  }
  size_t o = (size_t)(b * (NCH + 1) + c) * NU + u;
  Pvhi[o] = ah; Pvlo[o] = al;
  if (u == 0) { Pshi[b * (NCH + 1) + c] = sh; Pslo[b * (NCH + 1) + c] = sl; }
}

// ---------------------------------------------------------------------------
// k3b: in-place exclusive shuffle-scan of NCH=256 chunk sums (4 per lane);
// slot [NCH] = total. wid<512: vector tables; wid in [512,520): scalars.
// ---------------------------------------------------------------------------
__global__ __launch_bounds__(256) void k3b_scan(
    float* __restrict__ Pvhi, float* __restrict__ Pvlo,
    float* __restrict__ Pshi, float* __restrict__ Pslo) {
  int wid = blockIdx.x * 4 + (threadIdx.x >> 6);
  int l = threadIdx.x & 63;
  if (wid < 512) {
    int b = wid >> 7;
    int half = (wid >> 6) & 1;
    int u = wid & 63;
    float* T = half ? Pvlo : Pvhi;
    size_t i0 = (size_t)(b * (NCH + 1) + 4 * l) * NU + u;
    float v0 = T[i0], v1 = T[i0 + NU], v2 = T[i0 + 2*NU], v3 = T[i0 + 3*NU];
    float lsum = v0 + v1 + v2 + v3, s = lsum;
#pragma unroll
    for (int off = 1; off < 64; off <<= 1) {
      float t = __shfl_up(s, off, 64);
      if (l >= off) s += t;
    }
    float e = s - lsum;            // exclusive prefix of this lane's chunks
    T[i0] = e;
    T[i0 + NU] = e + v0;
    T[i0 + 2*NU] = e + v0 + v1;
    T[i0 + 3*NU] = e + v0 + v1 + v2;
    if (l == 63) T[(size_t)(b * (NCH + 1) + NCH) * NU + u] = s;
  } else if (wid < 520) {
    int s2 = wid - 512;
    int b = s2 >> 1;
    float* T = (s2 & 1) ? Pslo : Pshi;
    int i0 = b * (NCH + 1) + 4 * l;
    float v0 = T[i0], v1 = T[i0 + 1], v2 = T[i0 + 2], v3 = T[i0 + 3];
    float lsum = v0 + v1 + v2 + v3, s = lsum;
#pragma unroll
    for (int off = 1; off < 64; off <<= 1) {
      float t = __shfl_up(s, off, 64);
      if (l >= off) s += t;
    }
    float e = s - lsum;
    T[i0] = e; T[i0 + 1] = e + v0; T[i0 + 2] = e + v0 + v1;
    T[i0 + 3] = e + v0 + v1 + v2;
    if (l == 63) T[b * (NCH + 1) + NCH] = s;
  }
}

// ---------------------------------------------------------------------------
// k4: per row: 2-round ballot lower_bound, chunk-table lookup, CH=16 exact
// correction over the straddling chunk, combine, write. wave = row; lane = u.
// ---------------------------------------------------------------------------
__global__ __launch_bounds__(256) void k4_out(
    const float* __restrict__ f1, const float* __restrict__ f2s,
    const float* __restrict__ h, const float4* __restrict__ sdat,
    const float* __restrict__ Pvhi, const float* __restrict__ Pvlo,
    const float* __restrict__ Pshi, const float* __restrict__ Pslo,
    float* __restrict__ out) {
  int u = threadIdx.x & 63;
  int wv = threadIdx.x >> 6;
  int row = blockIdx.x * 4 + wv;    // [0, B*N)
  int b = row >> 12;
  const float* fs = f2s + b * NN;
  float fv = f1[row];
  float theta = -fv;
  // fan-out lower_bound: first t with fs[t] >= theta
  float q1 = fs[u * 64 + 63];
  int n1 = __popcll(__ballot(q1 < theta));   // # 64-blocks entirely < theta
  int t;
  if (n1 == 64) {
    t = NN;
  } else {
    float q2 = fs[n1 * 64 + u];
    t = n1 * 64 + __popcll(__ballot(q2 < theta));
  }
  int c = t >> 4; if (c > NCH - 1) c = NCH - 1;
  int k0 = b * NN + c * CH;
  const float* hb = h + (size_t)b * NN * NU;
  float ch = 0.f, cl = 0.f, csh = 0.f, csl = 0.f;
#pragma unroll
  for (int k = 0; k < CH; ++k) {
    int kg = c * CH + k;
    float4 e = sdat[k0 + k];
    int j = __float_as_int(e.w);
    float hv = hb[(size_t)j * NU + u];
    bool hi = (kg >= t);
    float wH = hi ? e.y : 0.f;
    float wL = hi ? 0.f : e.z;
    ch += wH * hv; cl += wL * hv; csh += wH; csl += wL;
  }
  size_t base = (size_t)b * (NCH + 1);
  size_t oc0 = (base + c) * NU + u;
  size_t oc1 = (base + c + 1) * NU + u;
  size_t oT  = (base + NCH) * NU + u;
  float Ahi = (Pvhi[oT] - Pvhi[oc1]) + ch;
  float Alo = Pvlo[oc0] + cl;
  float Shi = (Pshi[base + NCH] - Pshi[base + c + 1]) + csh;
  float Slo = Pslo[base + c] + csl;
  float e1 = expf(fv), e1l = expf(LEAKY * fv);
  float den = e1 * Shi + e1l * Slo;
  out[(size_t)row * NU + u] = (e1 * Ahi + e1l * Alo) / den;
}

// ---------------------------------------------------------------------------
extern "C" void kernel_launch(void* const* d_in, const int* in_sizes, int n_in,
                              void* d_out, int out_size, void* d_ws, size_t ws_size,
                              hipStream_t stream) {
  const float* x = (const float*)d_in[0];   // (4,4096,128) f32
  const float* W = (const float*)d_in[1];   // (128,64) f32
  const float* a = (const float*)d_in[2];   // (128,1) f32
  float* out = (float*)d_out;               // (4,4096,64) f32
  float* ws = (float*)d_ws;

  size_t o = 0;
  float* h    = ws + o; o += (size_t)NBATCH * NN * NU;        // 4 MB
  float* f1   = ws + o; o += (size_t)NBATCH * NN;
  float* f2   = ws + o; o += (size_t)NBATCH * NN;
  float* f2s  = ws + o; o += (size_t)NBATCH * NN;
  float4* sdat = (float4*)(ws + o); o += (size_t)NBATCH * NN * 4;  // 16B aligned
  float* Pvhi = ws + o; o += (size_t)NBATCH * (NCH + 1) * NU;
  float* Pvlo = ws + o; o += (size_t)NBATCH * (NCH + 1) * NU;
  float* Pshi = ws + o; o += (size_t)NBATCH * (NCH + 1);
  float* Pslo = ws + o; o += (size_t)NBATCH * (NCH + 1);
  unsigned short* pc = (unsigned short*)(ws + o); o += (size_t)NBATCH * 16 * NN / 2;
  // ~6 MB of ws

  k1_h<<<(NBATCH * NN) / 16, 256, 0, stream>>>(x, W, a, h, f1, f2);
  k2a_count<<<512, 256, 0, stream>>>(f2, pc);
  k2b_scatter<<<NBATCH * 16, 256, 0, stream>>>(f2, pc, sdat, f2s);
  k3_csum<<<(NBATCH * NCH) / 4, 256, 0, stream>>>(h, sdat, Pvhi, Pvlo, Pshi, Pslo);
  k3b_scan<<<130, 256, 0, stream>>>(Pvhi, Pvlo, Pshi, Pslo);
  k4_out<<<(NBATCH * NN) / 4, 256, 0, stream>>>(f1, f2s, h, sdat,
      Pvhi, Pvlo, Pshi, Pslo, out);
}

// Round 6
// 112.462 us; speedup vs baseline: 1.1407x; 1.1407x over previous
//
#include <hip/hip_runtime.h>
#include <hip/hip_bf16.h>

#define NBATCH 4
#define NN 4096
#define NF 128
#define NU 64
#define CH 16              // correction chunk length
#define NCH (NN / CH)      // 256 chunks per batch
#define LEAKY 0.2f

// ---------------------------------------------------------------------------
// k1: h[b,n,u] = sum_f x[b,n,f]*W[f,u]; f1 = h.a1, f2 = h.a2.
// 1024 blocks x 256 thr; 16 rows/block; wave owns 4 rows; lane = u.
// x staged in LDS (float4 broadcast reads); W from global (L1-hot).
// NOTE: scalar-load (s_load) streaming of x was tried and regressed 20us —
// SMEM pipe + SGPR pressure serialize. Keep the LDS path.
// ---------------------------------------------------------------------------
__global__ __launch_bounds__(256) void k1_h(
    const float* __restrict__ x, const float* __restrict__ W,
    const float* __restrict__ a,
    float* __restrict__ h, float* __restrict__ f1, float* __restrict__ f2) {
  __shared__ float xs[16][NF];   // 8 KB
  int tid = threadIdx.x;
  int row0 = blockIdx.x * 16;
  const float4* xg = (const float4*)(x + (size_t)row0 * NF);
  float4* xs4 = (float4*)xs;
  for (int k = tid; k < 16 * NF / 4; k += 256) xs4[k] = xg[k];
  __syncthreads();
  int u = tid & 63;
  int wv = tid >> 6;
  float acc[4] = {0.f, 0.f, 0.f, 0.f};
#pragma unroll 4
  for (int f = 0; f < NF; f += 4) {
    float w0 = W[(f+0)*NU+u], w1 = W[(f+1)*NU+u],
          w2 = W[(f+2)*NU+u], w3 = W[(f+3)*NU+u];
#pragma unroll
    for (int r = 0; r < 4; ++r) {
      float4 xv = *(const float4*)&xs[wv*4+r][f];
      acc[r] += xv.x*w0 + xv.y*w1 + xv.z*w2 + xv.w*w3;
    }
  }
  float a1 = a[u], a2 = a[NU+u];
#pragma unroll
  for (int r = 0; r < 4; ++r) {
    int grow = row0 + wv*4 + r;
    h[(size_t)grow*NU+u] = acc[r];
    float p1 = acc[r]*a1, p2 = acc[r]*a2;
#pragma unroll
    for (int off = 32; off >= 1; off >>= 1) {
      p1 += __shfl_xor(p1, off, 64);
      p2 += __shfl_xor(p2, off, 64);
    }
    if (u == 0) { f1[grow] = p1; f2[grow] = p2; }
  }
}

// ---------------------------------------------------------------------------
// k2a: partial rank counts. grid = b(4) x jc(8: 512 j) x kc(16: 256 k) = 512.
// Thread owns 2 j's; float4 LDS reads (8 compares per DS instr).
// ---------------------------------------------------------------------------
__global__ __launch_bounds__(256) void k2a_count(
    const float* __restrict__ f2, unsigned short* __restrict__ pc) {
  __shared__ float fsk[256];
  int b = blockIdx.x >> 7;          // 128 blocks per batch
  int jc = (blockIdx.x >> 4) & 7;
  int kc = blockIdx.x & 15;
  int tid = threadIdx.x;
  const float* f2b = f2 + b * NN;
  fsk[tid] = f2b[kc * 256 + tid];
  __syncthreads();
  int j0 = jc * 512 + tid;
  int j1 = j0 + 256;
  float my0 = f2b[j0], my1 = f2b[j1];
  int k0g = kc * 256;
  int cnt0 = 0, cnt1 = 0;
#pragma unroll 8
  for (int k = 0; k < 256; k += 4) {
    float4 v = *(const float4*)&fsk[k];
    int kg = k0g + k;
    cnt0 += (v.x < my0) || (v.x == my0 && kg + 0 < j0);
    cnt0 += (v.y < my0) || (v.y == my0 && kg + 1 < j0);
    cnt0 += (v.z < my0) || (v.z == my0 && kg + 2 < j0);
    cnt0 += (v.w < my0) || (v.w == my0 && kg + 3 < j0);
    cnt1 += (v.x < my1) || (v.x == my1 && kg + 0 < j1);
    cnt1 += (v.y < my1) || (v.y == my1 && kg + 1 < j1);
    cnt1 += (v.z < my1) || (v.z == my1 && kg + 2 < j1);
    cnt1 += (v.w < my1) || (v.w == my1 && kg + 3 < j1);
  }
  size_t base = ((size_t)(b * 16 + kc)) * NN;
  pc[base + j0] = (unsigned short)cnt0;
  pc[base + j1] = (unsigned short)cnt1;
}

// ---------------------------------------------------------------------------
// k2b: rank = sum of 16 partials; scatter packed {f2, e^f2, e^.2f2, perm}
// plus a plain sorted-f2 array for the k4 search.
// ---------------------------------------------------------------------------
__global__ __launch_bounds__(256) void k2b_scatter(
    const float* __restrict__ f2, const unsigned short* __restrict__ pc,
    float4* __restrict__ sdat, float* __restrict__ f2s) {
  int b = blockIdx.x >> 4;
  int jc = blockIdx.x & 15;
  int j = jc * 256 + threadIdx.x;
  float my = f2[b * NN + j];
  int rank = 0;
#pragma unroll
  for (int kc = 0; kc < 16; ++kc)
    rank += pc[((size_t)(b * 16 + kc)) * NN + j];
  int o = b * NN + rank;
  float4 v;
  v.x = my; v.y = expf(my); v.z = expf(LEAKY * my); v.w = __int_as_float(j);
  sdat[o] = v;
  f2s[o] = my;
}

// ---------------------------------------------------------------------------
// k3: chunk sums. One wave per chunk of CH=16 sorted els; lane = u.
// 256 blocks x 4 waves.
// ---------------------------------------------------------------------------
__global__ __launch_bounds__(256) void k3_csum(
    const float* __restrict__ h, const float4* __restrict__ sdat,
    float* __restrict__ Pvhi, float* __restrict__ Pvlo,
    float* __restrict__ Pshi, float* __restrict__ Pslo) {
  int u = threadIdx.x & 63;
  int wv = threadIdx.x >> 6;
  int cg = blockIdx.x * 4 + wv;     // global chunk 0..1023
  int b = cg >> 8;                  // 256 chunks per batch
  int c = cg & (NCH - 1);
  int k0 = b * NN + c * CH;
  const float* hb = h + (size_t)b * NN * NU;
  float ah = 0.f, al = 0.f, sh = 0.f, sl = 0.f;
#pragma unroll
  for (int k = 0; k < CH; ++k) {
    float4 e = sdat[k0 + k];
    int j = __float_as_int(e.w);
    float hv = hb[(size_t)j * NU + u];
    ah += e.y * hv; al += e.z * hv; sh += e.y; sl += e.z;
  }
  size_t o = (size_t)(b * (NCH + 1) + c) * NU + u;
  Pvhi[o] = ah; Pvlo[o] = al;
  if (u == 0) { Pshi[b * (NCH + 1) + c] = sh; Pslo[b * (NCH + 1) + c] = sl; }
}

// ---------------------------------------------------------------------------
// k3b: in-place exclusive shuffle-scan of NCH=256 chunk sums (4 per lane);
// slot [NCH] = total. wid<512: vector tables; wid in [512,520): scalars.
// ---------------------------------------------------------------------------
__global__ __launch_bounds__(256) void k3b_scan(
    float* __restrict__ Pvhi, float* __restrict__ Pvlo,
    float* __restrict__ Pshi, float* __restrict__ Pslo) {
  int wid = blockIdx.x * 4 + (threadIdx.x >> 6);
  int l = threadIdx.x & 63;
  if (wid < 512) {
    int b = wid >> 7;
    int half = (wid >> 6) & 1;
    int u = wid & 63;
    float* T = half ? Pvlo : Pvhi;
    size_t i0 = (size_t)(b * (NCH + 1) + 4 * l) * NU + u;
    float v0 = T[i0], v1 = T[i0 + NU], v2 = T[i0 + 2*NU], v3 = T[i0 + 3*NU];
    float lsum = v0 + v1 + v2 + v3, s = lsum;
#pragma unroll
    for (int off = 1; off < 64; off <<= 1) {
      float t = __shfl_up(s, off, 64);
      if (l >= off) s += t;
    }
    float e = s - lsum;            // exclusive prefix of this lane's chunks
    T[i0] = e;
    T[i0 + NU] = e + v0;
    T[i0 + 2*NU] = e + v0 + v1;
    T[i0 + 3*NU] = e + v0 + v1 + v2;
    if (l == 63) T[(size_t)(b * (NCH + 1) + NCH) * NU + u] = s;
  } else if (wid < 520) {
    int s2 = wid - 512;
    int b = s2 >> 1;
    float* T = (s2 & 1) ? Pslo : Pshi;
    int i0 = b * (NCH + 1) + 4 * l;
    float v0 = T[i0], v1 = T[i0 + 1], v2 = T[i0 + 2], v3 = T[i0 + 3];
    float lsum = v0 + v1 + v2 + v3, s = lsum;
#pragma unroll
    for (int off = 1; off < 64; off <<= 1) {
      float t = __shfl_up(s, off, 64);
      if (l >= off) s += t;
    }
    float e = s - lsum;
    T[i0] = e; T[i0 + 1] = e + v0; T[i0 + 2] = e + v0 + v1;
    T[i0 + 3] = e + v0 + v1 + v2;
    if (l == 63) T[b * (NCH + 1) + NCH] = s;
  }
}

// ---------------------------------------------------------------------------
// k4: per row: 2-round ballot lower_bound, chunk-table lookup, CH=16 exact
// correction over the straddling chunk, combine, write. wave = row; lane = u.
// ---------------------------------------------------------------------------
__global__ __launch_bounds__(256) void k4_out(
    const float* __restrict__ f1, const float* __restrict__ f2s,
    const float* __restrict__ h, const float4* __restrict__ sdat,
    const float* __restrict__ Pvhi, const float* __restrict__ Pvlo,
    const float* __restrict__ Pshi, const float* __restrict__ Pslo,
    float* __restrict__ out) {
  int u = threadIdx.x & 63;
  int wv = threadIdx.x >> 6;
  int row = blockIdx.x * 4 + wv;    // [0, B*N)
  int b = row >> 12;
  const float* fs = f2s + b * NN;
  float fv = f1[row];
  float theta = -fv;
  // fan-out lower_bound: first t with fs[t] >= theta
  float q1 = fs[u * 64 + 63];
  int n1 = __popcll(__ballot(q1 < theta));   // # 64-blocks entirely < theta
  int t;
  if (n1 == 64) {
    t = NN;
  } else {
    float q2 = fs[n1 * 64 + u];
    t = n1 * 64 + __popcll(__ballot(q2 < theta));
  }
  int c = t >> 4; if (c > NCH - 1) c = NCH - 1;
  int k0 = b * NN + c * CH;
  const float* hb = h + (size_t)b * NN * NU;
  float ch = 0.f, cl = 0.f, csh = 0.f, csl = 0.f;
#pragma unroll
  for (int k = 0; k < CH; ++k) {
    int kg = c * CH + k;
    float4 e = sdat[k0 + k];
    int j = __float_as_int(e.w);
    float hv = hb[(size_t)j * NU + u];
    bool hi = (kg >= t);
    float wH = hi ? e.y : 0.f;
    float wL = hi ? 0.f : e.z;
    ch += wH * hv; cl += wL * hv; csh += wH; csl += wL;
  }
  size_t base = (size_t)b * (NCH + 1);
  size_t oc0 = (base + c) * NU + u;
  size_t oc1 = (base + c + 1) * NU + u;
  size_t oT  = (base + NCH) * NU + u;
  float Ahi = (Pvhi[oT] - Pvhi[oc1]) + ch;
  float Alo = Pvlo[oc0] + cl;
  float Shi = (Pshi[base + NCH] - Pshi[base + c + 1]) + csh;
  float Slo = Pslo[base + c] + csl;
  float e1 = expf(fv), e1l = expf(LEAKY * fv);
  float den = e1 * Shi + e1l * Slo;
  out[(size_t)row * NU + u] = (e1 * Ahi + e1l * Alo) / den;
}

// ---------------------------------------------------------------------------
extern "C" void kernel_launch(void* const* d_in, const int* in_sizes, int n_in,
                              void* d_out, int out_size, void* d_ws, size_t ws_size,
                              hipStream_t stream) {
  const float* x = (const float*)d_in[0];   // (4,4096,128) f32
  const float* W = (const float*)d_in[1];   // (128,64) f32
  const float* a = (const float*)d_in[2];   // (128,1) f32
  float* out = (float*)d_out;               // (4,4096,64) f32
  float* ws = (float*)d_ws;

  size_t o = 0;
  float* h    = ws + o; o += (size_t)NBATCH * NN * NU;        // 4 MB
  float* f1   = ws + o; o += (size_t)NBATCH * NN;
  float* f2   = ws + o; o += (size_t)NBATCH * NN;
  float* f2s  = ws + o; o += (size_t)NBATCH * NN;
  float4* sdat = (float4*)(ws + o); o += (size_t)NBATCH * NN * 4;  // 16B aligned
  float* Pvhi = ws + o; o += (size_t)NBATCH * (NCH + 1) * NU;
  float* Pvlo = ws + o; o += (size_t)NBATCH * (NCH + 1) * NU;
  float* Pshi = ws + o; o += (size_t)NBATCH * (NCH + 1);
  float* Pslo = ws + o; o += (size_t)NBATCH * (NCH + 1);
  unsigned short* pc = (unsigned short*)(ws + o); o += (size_t)NBATCH * 16 * NN / 2;
  // ~6 MB of ws

  k1_h<<<(NBATCH * NN) / 16, 256, 0, stream>>>(x, W, a, h, f1, f2);
  k2a_count<<<512, 256, 0, stream>>>(f2, pc);
  k2b_scatter<<<NBATCH * 16, 256, 0, stream>>>(f2, pc, sdat, f2s);
  k3_csum<<<(NBATCH * NCH) / 4, 256, 0, stream>>>(h, sdat, Pvhi, Pvlo, Pshi, Pslo);
  k3b_scan<<<130, 256, 0, stream>>>(Pvhi, Pvlo, Pshi, Pslo);
  k4_out<<<(NBATCH * NN) / 4, 256, 0, stream>>>(f1, f2s, h, sdat,
      Pvhi, Pvlo, Pshi, Pslo, out);
}